// Round 9
// baseline (252.580 us; speedup 1.0000x reference)
//
#include <hip/hip_runtime.h>
#include <stdint.h>

// Problem constants (fixed instance)
#define B_    32
#define S_    4096
#define E_    256
#define P_    256
#define M_    16
#define G_    (B_*P_)      // 8192 groups
#define NSLOT (G_*M_)      // 131072 slots (== tokens)
#define GPW   8            // groups per workgroup
#define ROWS  128          // 8 groups * 16 slots
#define NWG   (G_/GPW)     // 1024 workgroups

typedef float fv4 __attribute__((ext_vector_type(4)));
typedef int   iv4 __attribute__((ext_vector_type(4)));
typedef int   iv2 __attribute__((ext_vector_type(2)));
typedef __bf16 bv8 __attribute__((ext_vector_type(8)));
typedef short  sv4 __attribute__((ext_vector_type(4)));

__device__ __forceinline__ uint32_t bf16rne(float f) {
  uint32_t u = __builtin_bit_cast(uint32_t, f);
  u += 0x7fffu + ((u >> 16) & 1u);
  return u >> 16;
}
__device__ __forceinline__ uint32_t pk2(uint32_t lo, uint32_t hi) {
  return (lo & 0xffffu) | (hi << 16);
}
// Builtins (NOT inline asm): hazard recognizer must see MFMAs (round-1 NaN).
__device__ __forceinline__ void mfma32(fv4& d, iv4 a, iv4 b) {
  d = __builtin_amdgcn_mfma_f32_16x16x32_bf16(
        __builtin_bit_cast(bv8, a), __builtin_bit_cast(bv8, b), d, 0, 0, 0);
}
__device__ __forceinline__ void mfma16(fv4& d, iv2 a, iv2 b) {
  d = __builtin_amdgcn_mfma_f32_16x16x16bf16_1k(
        __builtin_bit_cast(sv4, a), __builtin_bit_cast(sv4, b), d, 0, 0, 0);
}
// async global->LDS, 16B/lane; LDS dest = wave-uniform base + lane*16.
__device__ __forceinline__ void gload_lds16(const void* g, void* l) {
  __builtin_amdgcn_global_load_lds(
      (const __attribute__((address_space(1))) uint32_t*)g,
      (__attribute__((address_space(3))) uint32_t*)l, 16, 0, 0);
}

// XOR swizzle for 512B rows: flips byte bits 4-6 by row&7 (involution).
#define SWZ(off, row) ((off) ^ (((row) & 7) << 4))
// [128 rows][128B] buffers (Q/K/V/C): per-row XOR of byte bits 4-6.
#define LQ(row, cb) ((row) * 128 + ((cb) ^ (((row) & 7) << 4)))

// Raw barrier + counted waits (T3/T4): loads stay in flight across barriers.
#define BAR()   { asm volatile("" ::: "memory"); __builtin_amdgcn_s_barrier(); \
                  asm volatile("" ::: "memory"); }
#define VMWAIT2 asm volatile("s_waitcnt vmcnt(2)" ::: "memory")
#define VMWAIT0 asm volatile("s_waitcnt vmcnt(0)" ::: "memory")
#define LGKM0   asm volatile("s_waitcnt lgkmcnt(0)" ::: "memory")

// ---------------- prep kernels ----------------
__global__ void k_init(int* cnt, int* s2t) {
  int i = blockIdx.x * 256 + threadIdx.x;
  if (i < G_) cnt[i] = 0;
  if (i < NSLOT) s2t[i] = -1;
}

__global__ void k_trans(const float* __restrict__ Wq, const float* __restrict__ Wk,
                        const float* __restrict__ Wv, const float* __restrict__ W0,
                        uint16_t* __restrict__ WT) {
  // WT: 4 concatenated [256][256] bf16, WT[w][n][k] = bf16(W[w][k][n])
  int o = blockIdx.x * 256 + threadIdx.x;     // 0..65535
  int wsel = blockIdx.y;
  const float* W = (wsel == 0) ? Wq : (wsel == 1) ? Wk : (wsel == 2) ? Wv : W0;
  int n = o >> 8, k = o & 255;
  WT[(size_t)wsel * 65536 + o] = (uint16_t)bf16rne(W[k * 256 + n]);
}

__global__ void k_rank(const int* __restrict__ pos, int* cnt, int* s2t) {
  int i = blockIdx.x * 256 + threadIdx.x;
  if (i >= B_ * S_) return;
  int p = pos[i];
  if (p < 0 || p >= P_) return;          // invalid -> dropped (stays -1)
  int b = i >> 12;                       // i / S_
  int g = (b << 8) + p;
  int r = atomicAdd(&cnt[g], 1);         // arbitrary slot order: attention is
  if (r < M_) s2t[g * M_ + r] = i;       // permutation-equivariant, so OK
}

// stage one QKV weight tile (32 KiB = 64 n-rows x 512B): 2 instrs/wave.
__device__ __forceinline__ void stage_qkv(const uint16_t* Wt, int c0, char* buf,
                                          int w, int l) {
  #pragma unroll
  for (int it = 0; it < 2; ++it) {
    int q = it * 16 + w;                 // 0..31, 1 KiB per instr
    int n = q * 2 + (l >> 5);            // local n-row 0..63
    int seg = l & 31;
    gload_lds16(reinterpret_cast<const char*>(Wt) + (size_t)(c0 + n) * 512 + SWZ(seg * 16, n),
                buf + q * 1024);
  }
}
// stage W0 k-slice tile (32 KiB = 256 n-rows x 128B): 2 instrs/wave.
__device__ __forceinline__ void stage_w0(const uint16_t* W0T, int c0, char* buf,
                                         int w, int l) {
  #pragma unroll
  for (int it = 0; it < 2; ++it) {
    int q = it * 16 + w;
    int n = q * 8 + (l >> 3);            // W0 row (output col) 0..255
    int off = (l & 7) * 16;
    gload_lds16(reinterpret_cast<const char*>(W0T) + (size_t)n * 512 + c0 * 2 + (off ^ ((n & 7) << 4)),
                buf + q * 1024);
  }
}

// ---------------- fused main kernel ----------------
// 1 WG = 8 groups = 128 rows, 1024 threads = 16 waves (1 WG/CU: 64 arch +
// 64 AGPR = 128 unified regs/wave = 4 waves/SIMD; measured across r2..r8).
// Chunk = 64 cols (2 heads), 4 chunks: HALF the barrier phases of r7/r8,
// 2x MFMA per phase, no pair-redundant softmax (16 pairs / 16 waves).
// LDS 128 KiB: bufA/B 32K each; Q/K/V/C [128][64]bf16 16K each.
// Tile stream Wq,Wk,Wv,W0 per chunk, 2-deep ping-pong, counted vmcnt.
// Ledger (2 instrs/wave/tile): at consumer slot own outstanding = 4
// (tiles t, t+1); VMWAIT2 completes tile t; VMWAIT0 only at hc=3.
__global__ __launch_bounds__(1024) void k_main(
    const float* __restrict__ emb, const int* __restrict__ s2t,
    const uint16_t* __restrict__ WT, float* __restrict__ out) {
  extern __shared__ char smem[];
  char* bufA = smem;            // 32 KiB
  char* bufB = smem + 32768;    // 32 KiB
  char* Qb = smem + 65536;      // 16 KiB [128][64] bf16, row-swizzled
  char* Kb = smem + 81920;
  char* Vb = smem + 98304;
  char* Cb = smem + 114688;

  const uint16_t* WqT = WT;
  const uint16_t* WkT = WT + 65536;
  const uint16_t* WvT = WT + 131072;
  const uint16_t* W0T = WT + 196608;

  const int tid = threadIdx.x;
  const int l = tid & 63;
  const int w = tid >> 6;           // wave 0..15
  const int lane15 = l & 15;
  const int lq = l >> 4;            // lane quad 0..3
  const int rb = w >> 1;            // 16-row block 0..7
  const int ch = w & 1;             // col half
  const int slot0 = blockIdx.x * ROWS;

  // ---- gather: 128 token rows -> bf16 X overlay on bufA+bufB (64 KiB) ----
  #pragma unroll 2
  for (int rl = 0; rl < 8; ++rl) {
    int row = w * 8 + rl;
    int t = s2t[slot0 + row];            // wave-uniform (scalar load)
    uint32_t u0 = 0, u1 = 0;
    if (t >= 0) {
      const float4 v = *reinterpret_cast<const float4*>(emb + (size_t)t * E_ + (l << 2));
      u0 = pk2(bf16rne(v.x), bf16rne(v.y));
      u1 = pk2(bf16rne(v.z), bf16rne(v.w));
    }
    iv2 val; val[0] = (int)u0; val[1] = (int)u1;
    *reinterpret_cast<iv2*>(smem + row * 512 + SWZ(l * 8, row)) = val;
  }
  __syncthreads();

  // ---- X A-fragments: rows rb*16..+16, full K (32 VGPR) ----
  iv4 xf[8];
  const int arow = rb * 16 + lane15;
  #pragma unroll
  for (int ks = 0; ks < 8; ++ks)
    xf[ks] = *reinterpret_cast<const iv4*>(smem + arow * 512 + SWZ(ks * 64 + lq * 16, arow));
  __syncthreads();   // all xf read; overlay region now reusable

  fv4 outacc[8];     // 16 rows x 128 cols per wave, persists across chunks
  #pragma unroll
  for (int i = 0; i < 8; ++i) outacc[i] = fv4{0.f, 0.f, 0.f, 0.f};

  // prologue: 2 tiles in flight
  stage_qkv(WqT, 0, bufA, w, l);
  stage_qkv(WkT, 0, bufB, w, l);

  for (int hc = 0; hc < 4; ++hc) {       // 4 chunks of 64 cols (2 heads)
    const int c0 = hc * 64;

    // QKV projection: wave computes 16 rows x 32 cols (16 MFMA) from `buf`
    #define COMPUTE_QKV(buf, dst)                                            \
    {                                                                        \
      fv4 a0 = fv4{0.f,0.f,0.f,0.f}, a1 = fv4{0.f,0.f,0.f,0.f};              \
      const int n0 = ch * 32 + lane15, n1 = ch * 32 + lane15 + 16;           \
      _Pragma("unroll")                                                      \
      for (int ks = 0; ks < 8; ++ks) {                                       \
        iv4 b0 = *reinterpret_cast<const iv4*>((buf) + n0 * 512 + SWZ(ks * 64 + lq * 16, n0)); \
        iv4 b1 = *reinterpret_cast<const iv4*>((buf) + n1 * 512 + SWZ(ks * 64 + lq * 16, n1)); \
        mfma32(a0, xf[ks], b0);                                              \
        mfma32(a1, xf[ks], b1);                                              \
      }                                                                      \
      _Pragma("unroll")                                                      \
      for (int r = 0; r < 4; ++r) {                                          \
        int row = rb * 16 + lq * 4 + r;                                      \
        *reinterpret_cast<uint16_t*>((dst) + LQ(row, n0 * 2)) =              \
            (uint16_t)bf16rne(a0[r]);                                        \
        *reinterpret_cast<uint16_t*>((dst) + LQ(row, n1 * 2)) =              \
            (uint16_t)bf16rne(a1[r]);                                        \
      }                                                                      \
    }

    // slot 0: Wq tile in bufA
    VMWAIT2; BAR();
    COMPUTE_QKV(bufA, Qb);
    LGKM0; BAR();
    stage_qkv(WvT, c0, bufA, w, l);      // issue Wv(hc)

    // slot 1: Wk tile in bufB
    VMWAIT2; BAR();
    COMPUTE_QKV(bufB, Kb);
    LGKM0; BAR();
    stage_w0(W0T, c0, bufB, w, l);       // issue W0(hc)

    // slot 2: Wv tile in bufA
    VMWAIT2; BAR();
    COMPUTE_QKV(bufA, Vb);
    LGKM0; BAR();
    if (hc < 3) stage_qkv(WqT, c0 + 64, bufA, w, l);   // issue Wq(hc+1)

    // ---- attention: pair = wave; group g = w>>1, head = 2*hc + (w&1) ----
    {
      const int g = w >> 1, hh = w & 1;
      const int frow = g * 16 + lane15;
      iv4 kf = *reinterpret_cast<const iv4*>(Kb + LQ(frow, hh * 64 + lq * 16));
      iv4 qf = *reinterpret_cast<const iv4*>(Qb + LQ(frow, hh * 64 + lq * 16));
      fv4 s = fv4{0.f, 0.f, 0.f, 0.f};
      mfma32(s, kf, qf);                 // swapped QK^T
      float mx = fmaxf(fmaxf(s[0], s[1]), fmaxf(s[2], s[3]));
      mx = fmaxf(mx, __shfl_xor(mx, 16));
      mx = fmaxf(mx, __shfl_xor(mx, 32));
      const float Cc = 0.25503373f;      // log2(e)/sqrt(32)
      float e0 = exp2f((s[0] - mx) * Cc), e1 = exp2f((s[1] - mx) * Cc);
      float e2 = exp2f((s[2] - mx) * Cc), e3 = exp2f((s[3] - mx) * Cc);
      float sum = e0 + e1 + e2 + e3;
      sum += __shfl_xor(sum, 16);
      sum += __shfl_xor(sum, 32);
      float inv = 1.0f / sum;
      iv2 pa; pa[0] = (int)pk2(bf16rne(e0 * inv), bf16rne(e1 * inv));
              pa[1] = (int)pk2(bf16rne(e2 * inv), bf16rne(e3 * inv));
      const int r0 = g * 16 + lq * 4;
      #pragma unroll
      for (int dvt = 0; dvt < 2; ++dvt) {
        int cb = (hh * 32 + dvt * 16 + lane15) * 2;
        uint32_t v0 = *reinterpret_cast<const uint16_t*>(Vb + LQ(r0 + 0, cb));
        uint32_t v1 = *reinterpret_cast<const uint16_t*>(Vb + LQ(r0 + 1, cb));
        uint32_t v2 = *reinterpret_cast<const uint16_t*>(Vb + LQ(r0 + 2, cb));
        uint32_t v3 = *reinterpret_cast<const uint16_t*>(Vb + LQ(r0 + 3, cb));
        iv2 bv; bv[0] = (int)pk2(v0, v1); bv[1] = (int)pk2(v2, v3);
        fv4 cacc = fv4{0.f, 0.f, 0.f, 0.f};
        mfma16(cacc, pa, bv);
        #pragma unroll
        for (int r = 0; r < 4; ++r)
          *reinterpret_cast<uint16_t*>(Cb + LQ(r0 + r, cb)) =
              (uint16_t)bf16rne(cacc[r]);
      }
    }

    // slot 3: W0 tile in bufB (LGKM0+BAR also publish attn's Cb writes)
    if (hc < 3) { VMWAIT2; } else { VMWAIT0; }
    LGKM0; BAR();
    #pragma unroll
    for (int ks = 0; ks < 2; ++ks) {
      int ar = rb * 16 + lane15;
      iv4 af = *reinterpret_cast<const iv4*>(Cb + LQ(ar, ks * 64 + lq * 16));
      #pragma unroll
      for (int nt = 0; nt < 8; ++nt) {
        int n = ch * 128 + nt * 16 + lane15;
        iv4 bfg = *reinterpret_cast<const iv4*>(
            bufB + n * 128 + ((ks * 64 + lq * 16) ^ ((n & 7) << 4)));
        mfma32(outacc[nt], af, bfg);
      }
    }
    BAR();
    if (hc < 3) stage_qkv(WkT, c0 + 64, bufB, w, l);   // issue Wk(hc+1)
    #undef COMPUTE_QKV
  } // hc

  // ---- scatter out (fp32, 64B segments per 16-lane group) ----
  #pragma unroll
  for (int r = 0; r < 4; ++r) {
    int t = s2t[slot0 + rb * 16 + lq * 4 + r];
    if (t < 0) continue;
    #pragma unroll
    for (int nt = 0; nt < 8; ++nt) {
      int col = ch * 128 + nt * 16 + lane15;
      out[(size_t)t * E_ + col] = outacc[nt][r];
    }
  }
}

extern "C" void kernel_launch(void* const* d_in, const int* in_sizes, int n_in,
                              void* d_out, int out_size, void* d_ws, size_t ws_size,
                              hipStream_t stream) {
  (void)in_sizes; (void)n_in; (void)out_size; (void)ws_size;
  const float* emb = (const float*)d_in[0];
  const float* Wq  = (const float*)d_in[1];
  const float* Wk  = (const float*)d_in[2];
  const float* Wv  = (const float*)d_in[3];
  const float* W0  = (const float*)d_in[4];
  const int*   pos = (const int*)d_in[5];
  float* out = (float*)d_out;

  // ws layout: cnt 32KB | s2t 512KB | WT(4x bf16 256x256) 512KB
  int* cnt = (int*)d_ws;
  int* s2t = (int*)((char*)d_ws + 32768);
  uint16_t* WT = (uint16_t*)((char*)d_ws + 32768 + 524288);

  (void)hipFuncSetAttribute(reinterpret_cast<const void*>(k_main),
                            hipFuncAttributeMaxDynamicSharedMemorySize, 131072);

  k_init <<<512, 256, 0, stream>>>(cnt, s2t);
  k_trans<<<dim3(256, 4), 256, 0, stream>>>(Wq, Wk, Wv, W0, WT);
  k_rank <<<512, 256, 0, stream>>>(pos, cnt, s2t);
  k_main <<<NWG, 1024, 131072, stream>>>(emb, s2t, WT, out);
}

// Round 10
// 200.291 us; speedup vs baseline: 1.2611x; 1.2611x over previous
//
#include <hip/hip_runtime.h>
#include <stdint.h>

// Problem constants (fixed instance)
#define B_    32
#define S_    4096
#define E_    256
#define P_    256
#define M_    16
#define G_    (B_*P_)      // 8192 groups
#define NSLOT (G_*M_)      // 131072 slots (== tokens)
#define GPW   8            // groups per workgroup
#define ROWS  128          // 8 groups * 16 slots
#define NWG   (G_/GPW)     // 1024 workgroups

typedef float fv4 __attribute__((ext_vector_type(4)));
typedef int   iv4 __attribute__((ext_vector_type(4)));
typedef int   iv2 __attribute__((ext_vector_type(2)));
typedef __bf16 bv8 __attribute__((ext_vector_type(8)));
typedef short  sv4 __attribute__((ext_vector_type(4)));

__device__ __forceinline__ uint32_t bf16rne(float f) {
  uint32_t u = __builtin_bit_cast(uint32_t, f);
  u += 0x7fffu + ((u >> 16) & 1u);
  return u >> 16;
}
__device__ __forceinline__ uint32_t pk2(uint32_t lo, uint32_t hi) {
  return (lo & 0xffffu) | (hi << 16);
}
// Builtins (NOT inline asm): hazard recognizer must see MFMAs (round-1 NaN).
__device__ __forceinline__ void mfma32(fv4& d, iv4 a, iv4 b) {
  d = __builtin_amdgcn_mfma_f32_16x16x32_bf16(
        __builtin_bit_cast(bv8, a), __builtin_bit_cast(bv8, b), d, 0, 0, 0);
}
__device__ __forceinline__ void mfma16(fv4& d, iv2 a, iv2 b) {
  d = __builtin_amdgcn_mfma_f32_16x16x16bf16_1k(
        __builtin_bit_cast(sv4, a), __builtin_bit_cast(sv4, b), d, 0, 0, 0);
}
// async global->LDS, 16B/lane; LDS dest = wave-uniform base + lane*16.
__device__ __forceinline__ void gload_lds16(const void* g, void* l) {
  __builtin_amdgcn_global_load_lds(
      (const __attribute__((address_space(1))) uint32_t*)g,
      (__attribute__((address_space(3))) uint32_t*)l, 16, 0, 0);
}

// XOR swizzle for 512B rows: flips byte bits 4-6 by row&7 (involution).
#define SWZ(off, row) ((off) ^ (((row) & 7) << 4))
// 64B-row buffers (Q/K/V/C [128][32]bf16) stored [pair][128B], pair-swizzled.
#define LQKV(row, cb) ( ((row) >> 1) * 128 + \
    (((((row) & 1) << 6) + (cb)) ^ ((((row) >> 1) & 7) << 4)) )

// Raw barrier + counted waits (T3/T4): loads stay in flight across barriers.
#define BAR()   { asm volatile("" ::: "memory"); __builtin_amdgcn_s_barrier(); \
                  asm volatile("" ::: "memory"); }
#define VMWAIT3 asm volatile("s_waitcnt vmcnt(3)" ::: "memory")
#define VMWAIT0 asm volatile("s_waitcnt vmcnt(0)" ::: "memory")
#define LGKM0   asm volatile("s_waitcnt lgkmcnt(0)" ::: "memory")

// ---------------- prep kernels ----------------
__global__ void k_init(int* cnt, int* s2t) {
  int i = blockIdx.x * 256 + threadIdx.x;
  if (i < G_) cnt[i] = 0;
  if (i < NSLOT) s2t[i] = -1;
}

__global__ void k_trans(const float* __restrict__ Wq, const float* __restrict__ Wk,
                        const float* __restrict__ Wv, const float* __restrict__ W0,
                        uint16_t* __restrict__ WT) {
  // WT: 4 concatenated [256][256] bf16, WT[w][n][k] = bf16(W[w][k][n])
  int o = blockIdx.x * 256 + threadIdx.x;     // 0..65535
  int wsel = blockIdx.y;
  const float* W = (wsel == 0) ? Wq : (wsel == 1) ? Wk : (wsel == 2) ? Wv : W0;
  int n = o >> 8, k = o & 255;
  WT[(size_t)wsel * 65536 + o] = (uint16_t)bf16rne(W[k * 256 + n]);
}

__global__ void k_rank(const int* __restrict__ pos, int* cnt, int* s2t) {
  int i = blockIdx.x * 256 + threadIdx.x;
  if (i >= B_ * S_) return;
  int p = pos[i];
  if (p < 0 || p >= P_) return;          // invalid -> dropped (stays -1)
  int b = i >> 12;                       // i / S_
  int g = (b << 8) + p;
  int r = atomicAdd(&cnt[g], 1);         // arbitrary slot order: attention is
  if (r < M_) s2t[g * M_ + r] = i;       // permutation-equivariant, so OK
}

// stage one QKV weight tile (16 KiB = 32 n-rows x 512B): 1 instr/wave.
__device__ __forceinline__ void stage_qkv(const uint16_t* Wt, int c0, char* buf,
                                          int w, int l) {
  int n = w * 2 + (l >> 5);              // local n-row 0..31
  int seg = l & 31;
  gload_lds16(reinterpret_cast<const char*>(Wt) + (size_t)(c0 + n) * 512 + SWZ(seg * 16, n),
              buf + w * 1024);
}
// stage W0 k-slice tile (16 KiB): [256 n][64B] as [128 pair][128B], swizzled.
__device__ __forceinline__ void stage_w0(const uint16_t* W0T, int c0, char* buf,
                                         int w, int l) {
  int pair = w * 8 + (l >> 3);           // 0..127
  int jp = ((l & 7) * 16) ^ ((pair & 7) << 4);
  int n = 2 * pair + (jp >> 6);
  gload_lds16(reinterpret_cast<const char*>(W0T) + (size_t)n * 512 + c0 * 2 + (jp & 63),
              buf + w * 1024);
}

// ---------------- fused main kernel ----------------
// 1 WG = 8 groups = 128 rows, 1024 threads = 16 waves (64 arch + 64 AGPR =
// 128 unified regs/wave = 4 waves/SIMD; arch file pinned to 64 for 1024-thr
// WGs — r3..r9 evidence — so per-phase live state must stay small: r9's
// wider phases spilled ~200MB and regressed).
// This round: merge the 3 QKV slots into ONE phase (3 tiles staged
// concurrently, sequential 8-MFMA blocks -> same live regs as r8's slot),
// cutting barrier phases ~66 -> ~26. Chunk = 32 cols (1 head).
// LDS 144 KiB: two 48K {Wq,Wk,Wv} sets ping-pong + 16K W0 + 4x8K Q/K/V/C.
// Ledger/wave: P1 issues W0(hc) [1 instr] then QKVset(hc+1) [3]; P3 needs
// W0(hc) = oldest of 4 -> vmcnt(3); next P1 needs QKVset = rest -> vmcnt(0)
// with a full chunk (~3 phases) of latency cover. VMWAIT0-before-BAR at P1
// entry; last chunk: only W0(7) outstanding -> vmcnt(0) at P3.
__global__ __launch_bounds__(1024) void k_main(
    const float* __restrict__ emb, const int* __restrict__ s2t,
    const uint16_t* __restrict__ WT, float* __restrict__ out) {
  extern __shared__ char smem[];
  char* set0 = smem;            // 48 KiB: Wq,Wk,Wv tiles (16K each)
  char* set1 = smem + 49152;    // 48 KiB
  char* w0b  = smem + 98304;    // 16 KiB W0 tile
  char* Qb = smem + 114688;     // 8 KiB [128][32] bf16, pair-swizzled
  char* Kb = smem + 122880;
  char* Vb = smem + 131072;
  char* Cb = smem + 139264;     // total 147456 B = 144 KiB

  const uint16_t* WqT = WT;
  const uint16_t* WkT = WT + 65536;
  const uint16_t* WvT = WT + 131072;
  const uint16_t* W0T = WT + 196608;

  const int tid = threadIdx.x;
  const int l = tid & 63;
  const int w = tid >> 6;           // wave 0..15
  const int lane15 = l & 15;
  const int lq = l >> 4;            // lane quad 0..3
  const int rb = w >> 1;            // 16-row block 0..7
  const int ch = w & 1;             // col half
  const int slot0 = blockIdx.x * ROWS;

  // ---- gather: 128 token rows -> bf16 X overlay on smem[0..64K) ----
  #pragma unroll 2
  for (int rl = 0; rl < 8; ++rl) {
    int row = w * 8 + rl;
    int t = s2t[slot0 + row];            // wave-uniform (scalar load)
    uint32_t u0 = 0, u1 = 0;
    if (t >= 0) {
      const float4 v = *reinterpret_cast<const float4*>(emb + (size_t)t * E_ + (l << 2));
      u0 = pk2(bf16rne(v.x), bf16rne(v.y));
      u1 = pk2(bf16rne(v.z), bf16rne(v.w));
    }
    iv2 val; val[0] = (int)u0; val[1] = (int)u1;
    *reinterpret_cast<iv2*>(smem + row * 512 + SWZ(l * 8, row)) = val;
  }
  __syncthreads();

  // ---- X A-fragments: rows rb*16..+16, full K (32 VGPR) ----
  iv4 xf[8];
  const int arow = rb * 16 + lane15;
  #pragma unroll
  for (int ks = 0; ks < 8; ++ks)
    xf[ks] = *reinterpret_cast<const iv4*>(smem + arow * 512 + SWZ(ks * 64 + lq * 16, arow));
  __syncthreads();   // all xf read; overlay region now reusable

  fv4 outacc[8];     // 16 rows x 128 cols per wave, persists across chunks
  #pragma unroll
  for (int i = 0; i < 8; ++i) outacc[i] = fv4{0.f, 0.f, 0.f, 0.f};

  // prologue: QKV set for chunk 0 (3 instrs/wave in flight)
  stage_qkv(WqT, 0, set0,         w, l);
  stage_qkv(WkT, 0, set0 + 16384, w, l);
  stage_qkv(WvT, 0, set0 + 32768, w, l);

  for (int hc = 0; hc < 8; ++hc) {       // 8 chunks of 32 cols (1 head)
    const int c0 = hc * 32;
    char* sc = (hc & 1) ? set1 : set0;   // current set (resident after P1 BAR)
    char* sn = (hc & 1) ? set0 : set1;   // next set (staged during P1..P3)

    // QKV projection: wave computes 16 rows x 16 cols (8 MFMA) from tile
    #define COMPUTE_QKV(buf, dst)                                            \
    {                                                                        \
      fv4 a0 = fv4{0.f,0.f,0.f,0.f};                                         \
      const int n0 = ch * 16 + lane15;                                       \
      _Pragma("unroll")                                                      \
      for (int ks = 0; ks < 8; ++ks) {                                       \
        iv4 b0 = *reinterpret_cast<const iv4*>((buf) + n0 * 512 + SWZ(ks * 64 + lq * 16, n0)); \
        mfma32(a0, xf[ks], b0);                                              \
      }                                                                      \
      _Pragma("unroll")                                                      \
      for (int r = 0; r < 4; ++r) {                                          \
        int row = rb * 16 + lq * 4 + r;                                      \
        *reinterpret_cast<uint16_t*>((dst) + LQKV(row, n0 * 2)) =            \
            (uint16_t)bf16rne(a0[r]);                                        \
      }                                                                      \
    }

    // ---- P1: QKV compute (+ issue W0(hc) and QKVset(hc+1)) ----
    VMWAIT0;                             // QKVset(hc) resident (issued 1 chunk ago)
    BAR();
    stage_w0(W0T, c0, w0b, w, l);        // oldest outstanding -> vmcnt(3) at P3
    if (hc < 7) {
      stage_qkv(WqT, c0 + 32, sn,         w, l);
      stage_qkv(WkT, c0 + 32, sn + 16384, w, l);
      stage_qkv(WvT, c0 + 32, sn + 32768, w, l);
    }
    COMPUTE_QKV(sc,         Qb);
    COMPUTE_QKV(sc + 16384, Kb);
    COMPUTE_QKV(sc + 32768, Vb);
    LGKM0;

    // ---- P2: attention; pair = (g = w>>1), head = hc; dup by ch ----
    BAR();
    {
      const int g = w >> 1;
      const int frow = g * 16 + lane15;
      iv4 kf = *reinterpret_cast<const iv4*>(Kb + LQKV(frow, lq * 16));
      iv4 qf = *reinterpret_cast<const iv4*>(Qb + LQKV(frow, lq * 16));
      fv4 s = fv4{0.f, 0.f, 0.f, 0.f};
      mfma32(s, kf, qf);                 // swapped QK^T
      float mx = fmaxf(fmaxf(s[0], s[1]), fmaxf(s[2], s[3]));
      mx = fmaxf(mx, __shfl_xor(mx, 16));
      mx = fmaxf(mx, __shfl_xor(mx, 32));
      const float Cc = 0.25503373f;      // log2(e)/sqrt(32)
      float e0 = exp2f((s[0] - mx) * Cc), e1 = exp2f((s[1] - mx) * Cc);
      float e2 = exp2f((s[2] - mx) * Cc), e3 = exp2f((s[3] - mx) * Cc);
      float sum = e0 + e1 + e2 + e3;
      sum += __shfl_xor(sum, 16);
      sum += __shfl_xor(sum, 32);
      float inv = 1.0f / sum;
      iv2 pa; pa[0] = (int)pk2(bf16rne(e0 * inv), bf16rne(e1 * inv));
              pa[1] = (int)pk2(bf16rne(e2 * inv), bf16rne(e3 * inv));
      const int r0 = g * 16 + lq * 4;
      const int cb = (ch * 16 + lane15) * 2;   // V col half by ch
      uint32_t v0 = *reinterpret_cast<const uint16_t*>(Vb + LQKV(r0 + 0, cb));
      uint32_t v1 = *reinterpret_cast<const uint16_t*>(Vb + LQKV(r0 + 1, cb));
      uint32_t v2 = *reinterpret_cast<const uint16_t*>(Vb + LQKV(r0 + 2, cb));
      uint32_t v3 = *reinterpret_cast<const uint16_t*>(Vb + LQKV(r0 + 3, cb));
      iv2 bv; bv[0] = (int)pk2(v0, v1); bv[1] = (int)pk2(v2, v3);
      fv4 cacc = fv4{0.f, 0.f, 0.f, 0.f};
      mfma16(cacc, pa, bv);
      #pragma unroll
      for (int r = 0; r < 4; ++r)
        *reinterpret_cast<uint16_t*>(Cb + LQKV(r0 + r, cb)) =
            (uint16_t)bf16rne(cacc[r]);
    }
    LGKM0;

    // ---- P3: out += ctx_chunk @ W0[c0:c0+32, :] ----
    if (hc < 7) { VMWAIT3; } else { VMWAIT0; }   // completes W0(hc)
    BAR();
    {
      int ar = rb * 16 + lane15;
      iv4 af = *reinterpret_cast<const iv4*>(Cb + LQKV(ar, lq * 16));
      #pragma unroll
      for (int nt = 0; nt < 8; ++nt) {
        int n = ch * 128 + nt * 16 + lane15;
        iv4 bfg = *reinterpret_cast<const iv4*>(
            w0b + (n >> 1) * 128 + ((((n & 1) << 6) + lq * 16) ^ (((n >> 1) & 7) << 4)));
        mfma32(outacc[nt], af, bfg);
      }
    }
    LGKM0;
    #undef COMPUTE_QKV
  } // hc

  // ---- scatter out (fp32, 64B segments per 16-lane group) ----
  #pragma unroll
  for (int r = 0; r < 4; ++r) {
    int t = s2t[slot0 + rb * 16 + lq * 4 + r];
    if (t < 0) continue;
    #pragma unroll
    for (int nt = 0; nt < 8; ++nt) {
      int col = ch * 128 + nt * 16 + lane15;
      out[(size_t)t * E_ + col] = outacc[nt][r];
    }
  }
}

extern "C" void kernel_launch(void* const* d_in, const int* in_sizes, int n_in,
                              void* d_out, int out_size, void* d_ws, size_t ws_size,
                              hipStream_t stream) {
  (void)in_sizes; (void)n_in; (void)out_size; (void)ws_size;
  const float* emb = (const float*)d_in[0];
  const float* Wq  = (const float*)d_in[1];
  const float* Wk  = (const float*)d_in[2];
  const float* Wv  = (const float*)d_in[3];
  const float* W0  = (const float*)d_in[4];
  const int*   pos = (const int*)d_in[5];
  float* out = (float*)d_out;

  // ws layout: cnt 32KB | s2t 512KB | WT(4x bf16 256x256) 512KB
  int* cnt = (int*)d_ws;
  int* s2t = (int*)((char*)d_ws + 32768);
  uint16_t* WT = (uint16_t*)((char*)d_ws + 32768 + 524288);

  (void)hipFuncSetAttribute(reinterpret_cast<const void*>(k_main),
                            hipFuncAttributeMaxDynamicSharedMemorySize, 147456);

  k_init <<<512, 256, 0, stream>>>(cnt, s2t);
  k_trans<<<dim3(256, 4), 256, 0, stream>>>(Wq, Wk, Wv, W0, WT);
  k_rank <<<512, 256, 0, stream>>>(pos, cnt, s2t);
  k_main <<<NWG, 1024, 147456, stream>>>(emb, s2t, WT, out);
}